// Round 7
// baseline (1368.160 us; speedup 1.0000x reference)
//
#include <hip/hip_runtime.h>
#include <math.h>

// Problem constants
#define B_  128
#define T_  512
#define W_  64
#define D_  128
#define C_  256
#define K_  12
#define TP_ 500           // T - K_STEPS
#define N_SAMPLES 768000  // K_ * TP_ * B_

typedef _Float16 half2v __attribute__((ext_vector_type(2)));
typedef _Float16 f16x8  __attribute__((ext_vector_type(8)));
typedef float    f32x4  __attribute__((ext_vector_type(4)));

__device__ __forceinline__ unsigned int pack2(float a, float b) {
  unsigned short ua = __builtin_bit_cast(unsigned short, (_Float16)a);
  unsigned short ub = __builtin_bit_cast(unsigned short, (_Float16)b);
  return (unsigned int)ua | ((unsigned int)ub << 16);
}

// ---------------------------------------------------------------------------
// Kernel 1: z_seq = l2norm(rr_windows @ We + be); also writes f16 copy z16.
// v2: shfl-based reduction (1 barrier instead of 8).
// ---------------------------------------------------------------------------
__global__ __launch_bounds__(128) void z_kernel(const float* __restrict__ rr,
                                                const float* __restrict__ We,
                                                const float* __restrict__ be,
                                                float* __restrict__ z_out,
                                                _Float16* __restrict__ z16) {
  int row = blockIdx.x;   // b*T + t
  int d   = threadIdx.x;  // 0..127
  __shared__ float s_rr[64];
  __shared__ float s_w[2];
  if (d < 64) s_rr[d] = rr[row * 64 + d];
  __syncthreads();
  float acc = be[d];
#pragma unroll
  for (int w = 0; w < 64; ++w) acc = fmaf(s_rr[w], We[w * 128 + d], acc);
  float ss = acc * acc;
#pragma unroll
  for (int s = 1; s <= 32; s <<= 1) ss += __shfl_xor(ss, s);
  if ((d & 63) == 0) s_w[d >> 6] = ss;
  __syncthreads();
  float inv = 1.0f / fmaxf(sqrtf(s_w[0] + s_w[1]), 1e-12f);
  float zv = acc * inv;
  z_out[row * 128 + d] = zv;
  z16[(size_t)row * 128 + d] = (_Float16)zv;
}

// ---------------------------------------------------------------------------
// Kernel 2a: wiT16[col][k] = f16(Wi[k][col])  (for MFMA B operand)
// ---------------------------------------------------------------------------
__global__ __launch_bounds__(256) void wiT_kernel(const float* __restrict__ Wi,
                                                  _Float16* __restrict__ wiT) {
  int id = blockIdx.x * 256 + threadIdx.x;  // 0..98303
  int k   = id / 768;
  int col = id % 768;
  wiT[(size_t)col * 128 + k] = (_Float16)Wi[id];
}

// ---------------------------------------------------------------------------
// Kernel 2: x_proj = z_seq @ Wi + bi (MFMA f16, stored f16).
// ---------------------------------------------------------------------------
__global__ __launch_bounds__(256, 2) void xproj_mfma(const _Float16* __restrict__ z16,
                                                     const _Float16* __restrict__ wiT,
                                                     const float* __restrict__ bi,
                                                     _Float16* __restrict__ xp) {
  int rb  = blockIdx.x * 128;   // row tile base (65536 rows)
  int cb  = blockIdx.y * 128;   // col tile base (768 cols)
  int tid  = threadIdx.x;
  int wv   = tid >> 6;
  int lane = tid & 63;
  int n15  = lane & 15;
  int q    = lane >> 4;

  __shared__ __align__(16) _Float16 sA[128 * 72];   // z rows   [m][64-k panel]
  __shared__ __align__(16) _Float16 sB[128 * 72];   // wiT cols [n][64-k panel]

  f32x4 acc[2][8];
#pragma unroll
  for (int a = 0; a < 2; ++a)
#pragma unroll
    for (int m = 0; m < 8; ++m) acc[a][m] = (f32x4){0.f, 0.f, 0.f, 0.f};

#pragma unroll
  for (int p = 0; p < 2; ++p) {   // K=128 in 2 panels of 64
#pragma unroll
    for (int it = 0; it < 4; ++it) {
      int id = tid + it * 256;    // 0..1023
      int r  = id >> 3;           // 0..127
      int c8 = (id & 7) * 8;      // 0..56
      *(uint4*)(&sA[r * 72 + c8]) =
          *(const uint4*)(z16 + (size_t)(rb + r) * 128 + p * 64 + c8);
      *(uint4*)(&sB[r * 72 + c8]) =
          *(const uint4*)(wiT + (size_t)(cb + r) * 128 + p * 64 + c8);
    }
    __syncthreads();
#pragma unroll
    for (int ks = 0; ks < 2; ++ks) {
      f16x8 bf[2];
#pragma unroll
      for (int ntl = 0; ntl < 2; ++ntl)
        bf[ntl] = *(const f16x8*)(&sB[((wv * 2 + ntl) * 16 + n15) * 72 + ks * 32 + q * 8]);
#pragma unroll
      for (int mt = 0; mt < 8; ++mt) {
        f16x8 af = *(const f16x8*)(&sA[(mt * 16 + n15) * 72 + ks * 32 + q * 8]);
        acc[0][mt] = __builtin_amdgcn_mfma_f32_16x16x32_f16(af, bf[0], acc[0][mt], 0, 0, 0);
        acc[1][mt] = __builtin_amdgcn_mfma_f32_16x16x32_f16(af, bf[1], acc[1][mt], 0, 0, 0);
      }
    }
    __syncthreads();
  }

  // epilogue: bias + f16 store
#pragma unroll
  for (int ntl = 0; ntl < 2; ++ntl) {
    int col = cb + (wv * 2 + ntl) * 16 + n15;
    float bb = bi[col];
#pragma unroll
    for (int mt = 0; mt < 8; ++mt) {
#pragma unroll
      for (int r = 0; r < 4; ++r) {
        int row = rb + mt * 16 + q * 4 + r;
        xp[(size_t)row * 768 + col] = (_Float16)(acc[ntl][mt][r] + bb);
      }
    }
  }
}

// ---------------------------------------------------------------------------
// Kernel 2b: WhT f16 pack for GRU
// ---------------------------------------------------------------------------
__global__ __launch_bounds__(256) void whT_kernel(const float* __restrict__ Wh,
                                                  unsigned int* __restrict__ whT) {
  int g = blockIdx.x * 256 + threadIdx.x;  // 0..98303
  int i = g / 768;
  int j = g % 768;
  float lo = Wh[(size_t)(2 * i) * 768 + j];
  float hi = Wh[(size_t)(2 * i + 1) * 768 + j];
  whT[(size_t)j * 128 + i] = pack2(lo, hi);
}

// ---------------------------------------------------------------------------
// Kernel 2c: wkT16[k][d][c] = f16(Wk_w[k][c][d])
// ---------------------------------------------------------------------------
__global__ __launch_bounds__(256) void wkT_kernel(const float* __restrict__ Wk_w,
                                                  _Float16* __restrict__ wkT) {
  int id = blockIdx.x * 256 + threadIdx.x;  // 0..393215
  int k = id >> 15;
  int rem = id & 32767;
  int c = rem >> 7;
  int d = rem & 127;
  wkT[((size_t)k * 128 + d) * 256 + c] = (_Float16)Wk_w[id];
}

// ---------------------------------------------------------------------------
// Kernel 3: GRU scan — R3 structure + split accumulator chains.
// Each gate's 8-deep dependent MFMA chain -> 2x4-deep (6 chains total),
// merged with one f32 add: exposed chain latency ~280 -> ~170 cy/step.
// Everything else identical to the proven R3 kernel (603 us).
// ---------------------------------------------------------------------------
__global__ __launch_bounds__(1024) void gru_kernel(const _Float16* __restrict__ xp,
                                                   const unsigned int* __restrict__ whT,
                                                   const float* __restrict__ bh,
                                                   float* __restrict__ c_out,
                                                   _Float16* __restrict__ c16) {
  __shared__ __align__(16) unsigned int s_h2[2][128];  // double-buffered packed h
  int tid  = threadIdx.x;
  int b    = blockIdx.x;
  int w    = tid >> 6;    // wave 0..15
  int lane = tid & 63;
  int n15  = lane & 15;
  int q    = lane >> 4;
  int ch   = w * 16 + n15;   // channel 0..255 (each covered by 4 q-replicas)

  uint4 wf[3][8];
#pragma unroll
  for (int g = 0; g < 3; ++g) {
    const uint4* src = (const uint4*)(whT + (size_t)(g * 256 + ch) * 128);
#pragma unroll
    for (int kt = 0; kt < 8; ++kt) wf[g][kt] = src[kt * 4 + q];
  }

  if (tid < 128) s_h2[0][tid] = 0u;

  float bhr = bh[ch], bhz = bh[256 + ch], bhn = bh[512 + ch];
  const _Float16* xb = xp + (size_t)b * 512 * 768;
  float xr_n = (float)xb[ch];
  float xz_n = (float)xb[256 + ch];
  float xn_n = (float)xb[512 + ch];
  float h = 0.f;
  __syncthreads();

  for (int t = 0; t < 512; ++t) {
    const char* hb = (const char*)(&s_h2[t & 1][0]) + q * 16;
    f32x4 a0 = (f32x4){0.f, 0.f, 0.f, 0.f};
    f32x4 a1 = (f32x4){0.f, 0.f, 0.f, 0.f};
    f32x4 a2 = (f32x4){0.f, 0.f, 0.f, 0.f};
    f32x4 d0 = (f32x4){0.f, 0.f, 0.f, 0.f};
    f32x4 d1 = (f32x4){0.f, 0.f, 0.f, 0.f};
    f32x4 d2 = (f32x4){0.f, 0.f, 0.f, 0.f};
#pragma unroll
    for (int kt = 0; kt < 4; ++kt) {
      f16x8 af = *(const f16x8*)(hb + kt * 64);   // uniform per q-group: broadcast
      a0 = __builtin_amdgcn_mfma_f32_16x16x32_f16(af, __builtin_bit_cast(f16x8, wf[0][kt]), a0, 0, 0, 0);
      a1 = __builtin_amdgcn_mfma_f32_16x16x32_f16(af, __builtin_bit_cast(f16x8, wf[1][kt]), a1, 0, 0, 0);
      a2 = __builtin_amdgcn_mfma_f32_16x16x32_f16(af, __builtin_bit_cast(f16x8, wf[2][kt]), a2, 0, 0, 0);
    }
#pragma unroll
    for (int kt = 4; kt < 8; ++kt) {
      f16x8 af = *(const f16x8*)(hb + kt * 64);
      d0 = __builtin_amdgcn_mfma_f32_16x16x32_f16(af, __builtin_bit_cast(f16x8, wf[0][kt]), d0, 0, 0, 0);
      d1 = __builtin_amdgcn_mfma_f32_16x16x32_f16(af, __builtin_bit_cast(f16x8, wf[1][kt]), d1, 0, 0, 0);
      d2 = __builtin_amdgcn_mfma_f32_16x16x32_f16(af, __builtin_bit_cast(f16x8, wf[2][kt]), d2, 0, 0, 0);
    }

    float xr_c = xr_n, xz_c = xz_n, xn_c = xn_n;
    if (t < 511) {
      const _Float16* p = xb + (size_t)(t + 1) * 768;
      xr_n = (float)p[ch];
      xz_n = (float)p[256 + ch];
      xn_n = (float)p[512 + ch];
    }

    float hr = (a0[0] + d0[0]) + bhr;
    float hz = (a1[0] + d1[0]) + bhz;
    float hn = (a2[0] + d2[0]) + bhn;
    float r = __builtin_amdgcn_rcpf(1.f + __expf(-(xr_c + hr)));
    float z = __builtin_amdgcn_rcpf(1.f + __expf(-(xz_c + hz)));
    float y = xn_c + r * hn;
    y = fminf(10.f, fmaxf(-10.f, y));
    float ey = __expf(-2.f * y);
    float n = (1.f - ey) * __builtin_amdgcn_rcpf(1.f + ey);
    h = (1.f - z) * n + z * h;

    if (q == 0) {
      ((_Float16*)(&s_h2[(t & 1) ^ 1][0]))[ch] = (_Float16)h;
      c_out[((size_t)b * 512 + t) * 256 + ch] = h;
      c16[((size_t)b * 512 + t) * 256 + ch] = (_Float16)h;
    }
    __syncthreads();
  }
}

// ---------------------------------------------------------------------------
// Kernel 4: MFMA-f16 fused CPC loss — EXACT R3 v2 (proven ~196 us).
// 6000 blocks, 2/CU; no global atomics (per-block float2 partial store).
// R5 (1-block/t amortization) and R6 (T14 reg-staging) both REGRESSED —
// this structure is the session's verified best.
// ---------------------------------------------------------------------------
__global__ __launch_bounds__(256, 2) void cpc_kernel(const _Float16* __restrict__ z16,
                                                     const _Float16* __restrict__ c16,
                                                     const _Float16* __restrict__ wkT,
                                                     const float* __restrict__ Wk_b,
                                                     float2* __restrict__ partials) {
  int k   = blockIdx.x;   // 0..11
  int t   = blockIdx.y;   // 0..499
  int tid = threadIdx.x;
  int wv   = tid >> 6;
  int lane = tid & 63;
  int n15  = lane & 15;
  int q    = lane >> 4;

  __shared__ __align__(16) _Float16 sA[128 * 72];
  __shared__ __align__(16) _Float16 sB[128 * 72];
  __shared__ __align__(16) _Float16 sP[128 * 136];
  __shared__ float s_bias[128];

  if (tid < 128) s_bias[tid] = Wk_b[k * 128 + tid];

  f32x4 acc[2][8];
#pragma unroll
  for (int a = 0; a < 2; ++a)
#pragma unroll
    for (int m = 0; m < 8; ++m) acc[a][m] = (f32x4){0.f, 0.f, 0.f, 0.f};

  const _Float16* wk_base = wkT + (size_t)k * 128 * 256;

  // ---- Phase B: P^T = Wk^T @ Ct^T, 4 c-panels of 64 ----
  for (int p = 0; p < 4; ++p) {
#pragma unroll
    for (int it = 0; it < 4; ++it) {
      int id = tid + it * 256;
      int r  = id >> 3;
      int c8 = (id & 7) * 8;
      *(uint4*)(&sA[r * 72 + c8]) =
          *(const uint4*)(wk_base + (size_t)r * 256 + p * 64 + c8);
      *(uint4*)(&sB[r * 72 + c8]) =
          *(const uint4*)(c16 + ((size_t)r * 512 + t) * 256 + p * 64 + c8);
    }
    __syncthreads();
#pragma unroll
    for (int ks = 0; ks < 2; ++ks) {
      f16x8 bf[2];
#pragma unroll
      for (int ntl = 0; ntl < 2; ++ntl)
        bf[ntl] = *(const f16x8*)(&sB[((wv * 2 + ntl) * 16 + n15) * 72 + ks * 32 + q * 8]);
#pragma unroll
      for (int mt = 0; mt < 8; ++mt) {
        f16x8 af = *(const f16x8*)(&sA[(mt * 16 + n15) * 72 + ks * 32 + q * 8]);
        acc[0][mt] = __builtin_amdgcn_mfma_f32_16x16x32_f16(af, bf[0], acc[0][mt], 0, 0, 0);
        acc[1][mt] = __builtin_amdgcn_mfma_f32_16x16x32_f16(af, bf[1], acc[1][mt], 0, 0, 0);
      }
    }
    __syncthreads();
  }

  // ---- bias + l2norm scale ----
  float scale[2];
#pragma unroll
  for (int ntl = 0; ntl < 2; ++ntl) {
    float ssq = 0.f;
#pragma unroll
    for (int mt = 0; mt < 8; ++mt)
#pragma unroll
      for (int r = 0; r < 4; ++r) {
        float v = acc[ntl][mt][r] + s_bias[mt * 16 + q * 4 + r];
        acc[ntl][mt][r] = v;
        ssq = fmaf(v, v, ssq);
      }
    ssq += __shfl_xor(ssq, 16);
    ssq += __shfl_xor(ssq, 32);
    scale[ntl] = 10.0f / fmaxf(sqrtf(ssq), 1e-12f);
  }

  // ---- write Pn[b][d] ----
#pragma unroll
  for (int ntl = 0; ntl < 2; ++ntl) {
    int bi = (wv * 2 + ntl) * 16 + n15;
#pragma unroll
    for (int mt = 0; mt < 8; ++mt) {
      uint2 v;
      v.x = pack2(acc[ntl][mt][0] * scale[ntl], acc[ntl][mt][1] * scale[ntl]);
      v.y = pack2(acc[ntl][mt][2] * scale[ntl], acc[ntl][mt][3] * scale[ntl]);
      *(uint2*)(&sP[bi * 136 + mt * 16 + q * 4]) = v;
    }
  }

  // ---- stage Zf ----
  int tz = t + k + 1;
#pragma unroll
  for (int it = 0; it < 4; ++it) {
    int id = tid + it * 256;
    int r  = id >> 3;
    int d8 = (id & 7) * 8;
    *(uint4*)(&sA[r * 72 + d8]) =
        *(const uint4*)(z16 + ((size_t)r * 512 + tz) * 128 + d8);
    *(uint4*)(&sB[r * 72 + d8]) =
        *(const uint4*)(z16 + ((size_t)r * 512 + tz) * 128 + 64 + d8);
  }
  __syncthreads();

  // ---- Phase D: logits ----
  f32x4 lacc[2][8];
#pragma unroll
  for (int a = 0; a < 2; ++a)
#pragma unroll
    for (int m = 0; m < 8; ++m) lacc[a][m] = (f32x4){0.f, 0.f, 0.f, 0.f};

#pragma unroll
  for (int pan = 0; pan < 2; ++pan) {
#pragma unroll
    for (int ks = 0; ks < 2; ++ks) {
      f16x8 af[2];
#pragma unroll
      for (int mtl = 0; mtl < 2; ++mtl)
        af[mtl] = *(const f16x8*)(&sP[((wv * 2 + mtl) * 16 + n15) * 136 + pan * 64 + ks * 32 + q * 8]);
#pragma unroll
      for (int nt = 0; nt < 8; ++nt) {
        f16x8 bf = pan
          ? *(const f16x8*)(&sB[(nt * 16 + n15) * 72 + ks * 32 + q * 8])
          : *(const f16x8*)(&sA[(nt * 16 + n15) * 72 + ks * 32 + q * 8]);
        lacc[0][nt] = __builtin_amdgcn_mfma_f32_16x16x32_f16(af[0], bf, lacc[0][nt], 0, 0, 0);
        lacc[1][nt] = __builtin_amdgcn_mfma_f32_16x16x32_f16(af[1], bf, lacc[1][nt], 0, 0, 0);
      }
    }
  }

  // ---- softmax stats + diag + argmax ----
  float loss_acc = 0.f, corr_acc = 0.f;
#pragma unroll
  for (int mtl = 0; mtl < 2; ++mtl) {
    int dnt = wv * 2 + mtl;
#pragma unroll
    for (int r = 0; r < 4; ++r) {
      int b = (wv * 2 + mtl) * 16 + q * 4 + r;
      float m = -1e30f; int idx = 1 << 30; float diag = 0.f;
#pragma unroll
      for (int nt = 0; nt < 8; ++nt) {
        float v = lacc[mtl][nt][r];
        int c2 = nt * 16 + n15;
        if (v > m) { m = v; idx = c2; }
        if (nt == dnt && n15 == (b & 15)) diag = v;
      }
#pragma unroll
      for (int s = 1; s <= 8; s <<= 1) {
        float om = __shfl_xor(m, s);
        int   oi = __shfl_xor(idx, s);
        if (om > m || (om == m && oi < idx)) { m = om; idx = oi; }
      }
      float e = 0.f;
#pragma unroll
      for (int nt = 0; nt < 8; ++nt) e += __expf(lacc[mtl][nt][r] - m);
#pragma unroll
      for (int s = 1; s <= 8; s <<= 1) e += __shfl_xor(e, s);
      if (n15 == (b & 15)) {
        float lse = m + __logf(e);
        loss_acc += lse - diag;
        corr_acc += (idx == b) ? 1.0f : 0.0f;
      }
    }
  }
#pragma unroll
  for (int s = 1; s <= 32; s <<= 1) {
    loss_acc += __shfl_xor(loss_acc, s);
    corr_acc += __shfl_xor(corr_acc, s);
  }

  // per-block reduction via (dead) s_bias region; ONE plain store per block
  if (lane == 0) {
    s_bias[wv * 2 + 0] = loss_acc;
    s_bias[wv * 2 + 1] = corr_acc;
  }
  __syncthreads();
  if (tid == 0) {
    float L = s_bias[0] + s_bias[2] + s_bias[4] + s_bias[6];
    float C = s_bias[1] + s_bias[3] + s_bias[5] + s_bias[7];
    partials[k * TP_ + t] = make_float2(L, C);
  }
}

// ---------------------------------------------------------------------------
// Kernel 5: final reduction of 6000 per-block partials -> out[0..1]
// ---------------------------------------------------------------------------
__global__ __launch_bounds__(256) void reduce_kernel(const float2* __restrict__ partials,
                                                     float* __restrict__ out) {
  float l = 0.f, c = 0.f;
  for (int i = threadIdx.x; i < K_ * TP_; i += 256) {
    float2 v = partials[i];
    l += v.x; c += v.y;
  }
#pragma unroll
  for (int s = 1; s <= 32; s <<= 1) {
    l += __shfl_xor(l, s);
    c += __shfl_xor(c, s);
  }
  __shared__ float sl[4], sc[4];
  int wv = threadIdx.x >> 6;
  if ((threadIdx.x & 63) == 0) { sl[wv] = l; sc[wv] = c; }
  __syncthreads();
  if (threadIdx.x == 0) {
    float L = sl[0] + sl[1] + sl[2] + sl[3];
    float C = sc[0] + sc[1] + sc[2] + sc[3];
    out[0] = L * (float)(1.0 / (double)N_SAMPLES);
    out[1] = C * (float)(100.0 / (double)N_SAMPLES);
  }
}

// ---------------------------------------------------------------------------
extern "C" void kernel_launch(void* const* d_in, const int* in_sizes, int n_in,
                              void* d_out, int out_size, void* d_ws, size_t ws_size,
                              hipStream_t stream) {
  (void)in_sizes; (void)n_in; (void)out_size; (void)ws_size;
  const float* rr  = (const float*)d_in[0];
  const float* We  = (const float*)d_in[1];
  const float* be  = (const float*)d_in[2];
  const float* Wi  = (const float*)d_in[3];
  const float* Wh  = (const float*)d_in[4];
  const float* bi  = (const float*)d_in[5];
  const float* bh  = (const float*)d_in[6];
  const float* Wkw = (const float*)d_in[7];
  const float* Wkb = (const float*)d_in[8];

  float* out = (float*)d_out;
  float* z   = out + 2;                              // (B,T,D) fp32
  float* c   = z + (size_t)B_ * T_ * D_;             // (B,T,C) fp32

  // workspace layout (bytes):
  //   whT    @ 0          (384 KB)
  //   wkT16  @ 393216     (768 KB)
  //   z16    @ 1179648    (16 MB)
  //   c16    @ 17956864   (32 MB)
  //   xp     @ 51511296   (100.7 MB)  <- dead after gru; first 48KB reused
  //                                      as cpc partials (float2[6000])
  //   wiT16  @ 152174592  (192 KB)
  char* ws = (char*)d_ws;
  unsigned int* whT   = (unsigned int*)ws;
  _Float16*     wkT16 = (_Float16*)(ws + 393216);
  _Float16*     z16   = (_Float16*)(ws + 1179648);
  _Float16*     c16   = (_Float16*)(ws + 17956864);
  _Float16*     xp    = (_Float16*)(ws + 51511296);
  _Float16*     wiT16 = (_Float16*)(ws + 152174592);
  float2*       parts = (float2*)(ws + 51511296);    // overlays dead xp

  hipMemsetAsync(d_out, 0, 2 * sizeof(float), stream);
  z_kernel<<<B_ * T_, 128, 0, stream>>>(rr, We, be, z, z16);
  wiT_kernel<<<384, 256, 0, stream>>>(Wi, wiT16);
  whT_kernel<<<384, 256, 0, stream>>>(Wh, whT);
  wkT_kernel<<<1536, 256, 0, stream>>>(Wkw, wkT16);
  xproj_mfma<<<dim3(512, 6), 256, 0, stream>>>(z16, wiT16, bi, xp);
  gru_kernel<<<B_, 1024, 0, stream>>>(xp, whT, bh, c, c16);
  cpc_kernel<<<dim3(K_, TP_), 256, 0, stream>>>(z16, c16, wkT16, Wkb, parts);
  reduce_kernel<<<1, 256, 0, stream>>>(parts, out);
}

// Round 8
// 982.917 us; speedup vs baseline: 1.3919x; 1.3919x over previous
//
#include <hip/hip_runtime.h>
#include <math.h>

// Problem constants
#define B_  128
#define T_  512
#define W_  64
#define D_  128
#define C_  256
#define K_  12
#define TP_ 500           // T - K_STEPS
#define N_SAMPLES 768000  // K_ * TP_ * B_

typedef _Float16 half2v __attribute__((ext_vector_type(2)));
typedef _Float16 f16x8  __attribute__((ext_vector_type(8)));
typedef float    f32x4  __attribute__((ext_vector_type(4)));

__device__ __forceinline__ unsigned int pack2(float a, float b) {
  unsigned short ua = __builtin_bit_cast(unsigned short, (_Float16)a);
  unsigned short ub = __builtin_bit_cast(unsigned short, (_Float16)b);
  return (unsigned int)ua | ((unsigned int)ub << 16);
}

// ---------------------------------------------------------------------------
// Kernel 1: z_seq = l2norm(rr_windows @ We + be); also writes f16 copy z16.
// v2: shfl-based reduction (1 barrier instead of 8) — kept from R7 (~17us win).
// ---------------------------------------------------------------------------
__global__ __launch_bounds__(128) void z_kernel(const float* __restrict__ rr,
                                                const float* __restrict__ We,
                                                const float* __restrict__ be,
                                                float* __restrict__ z_out,
                                                _Float16* __restrict__ z16) {
  int row = blockIdx.x;   // b*T + t
  int d   = threadIdx.x;  // 0..127
  __shared__ float s_rr[64];
  __shared__ float s_w[2];
  if (d < 64) s_rr[d] = rr[row * 64 + d];
  __syncthreads();
  float acc = be[d];
#pragma unroll
  for (int w = 0; w < 64; ++w) acc = fmaf(s_rr[w], We[w * 128 + d], acc);
  float ss = acc * acc;
#pragma unroll
  for (int s = 1; s <= 32; s <<= 1) ss += __shfl_xor(ss, s);
  if ((d & 63) == 0) s_w[d >> 6] = ss;
  __syncthreads();
  float inv = 1.0f / fmaxf(sqrtf(s_w[0] + s_w[1]), 1e-12f);
  float zv = acc * inv;
  z_out[row * 128 + d] = zv;
  z16[(size_t)row * 128 + d] = (_Float16)zv;
}

// ---------------------------------------------------------------------------
// Kernel 2a: wiT16[col][k] = f16(Wi[k][col])  (for MFMA B operand)
// ---------------------------------------------------------------------------
__global__ __launch_bounds__(256) void wiT_kernel(const float* __restrict__ Wi,
                                                  _Float16* __restrict__ wiT) {
  int id = blockIdx.x * 256 + threadIdx.x;  // 0..98303
  int k   = id / 768;
  int col = id % 768;
  wiT[(size_t)col * 128 + k] = (_Float16)Wi[id];
}

// ---------------------------------------------------------------------------
// Kernel 2: x_proj = z_seq @ Wi + bi (MFMA f16, stored f16).
// ---------------------------------------------------------------------------
__global__ __launch_bounds__(256, 2) void xproj_mfma(const _Float16* __restrict__ z16,
                                                     const _Float16* __restrict__ wiT,
                                                     const float* __restrict__ bi,
                                                     _Float16* __restrict__ xp) {
  int rb  = blockIdx.x * 128;   // row tile base (65536 rows)
  int cb  = blockIdx.y * 128;   // col tile base (768 cols)
  int tid  = threadIdx.x;
  int wv   = tid >> 6;
  int lane = tid & 63;
  int n15  = lane & 15;
  int q    = lane >> 4;

  __shared__ __align__(16) _Float16 sA[128 * 72];   // z rows   [m][64-k panel]
  __shared__ __align__(16) _Float16 sB[128 * 72];   // wiT cols [n][64-k panel]

  f32x4 acc[2][8];
#pragma unroll
  for (int a = 0; a < 2; ++a)
#pragma unroll
    for (int m = 0; m < 8; ++m) acc[a][m] = (f32x4){0.f, 0.f, 0.f, 0.f};

#pragma unroll
  for (int p = 0; p < 2; ++p) {   // K=128 in 2 panels of 64
#pragma unroll
    for (int it = 0; it < 4; ++it) {
      int id = tid + it * 256;    // 0..1023
      int r  = id >> 3;           // 0..127
      int c8 = (id & 7) * 8;      // 0..56
      *(uint4*)(&sA[r * 72 + c8]) =
          *(const uint4*)(z16 + (size_t)(rb + r) * 128 + p * 64 + c8);
      *(uint4*)(&sB[r * 72 + c8]) =
          *(const uint4*)(wiT + (size_t)(cb + r) * 128 + p * 64 + c8);
    }
    __syncthreads();
#pragma unroll
    for (int ks = 0; ks < 2; ++ks) {
      f16x8 bf[2];
#pragma unroll
      for (int ntl = 0; ntl < 2; ++ntl)
        bf[ntl] = *(const f16x8*)(&sB[((wv * 2 + ntl) * 16 + n15) * 72 + ks * 32 + q * 8]);
#pragma unroll
      for (int mt = 0; mt < 8; ++mt) {
        f16x8 af = *(const f16x8*)(&sA[(mt * 16 + n15) * 72 + ks * 32 + q * 8]);
        acc[0][mt] = __builtin_amdgcn_mfma_f32_16x16x32_f16(af, bf[0], acc[0][mt], 0, 0, 0);
        acc[1][mt] = __builtin_amdgcn_mfma_f32_16x16x32_f16(af, bf[1], acc[1][mt], 0, 0, 0);
      }
    }
    __syncthreads();
  }

  // epilogue: bias + f16 store
#pragma unroll
  for (int ntl = 0; ntl < 2; ++ntl) {
    int col = cb + (wv * 2 + ntl) * 16 + n15;
    float bb = bi[col];
#pragma unroll
    for (int mt = 0; mt < 8; ++mt) {
#pragma unroll
      for (int r = 0; r < 4; ++r) {
        int row = rb + mt * 16 + q * 4 + r;
        xp[(size_t)row * 768 + col] = (_Float16)(acc[ntl][mt][r] + bb);
      }
    }
  }
}

// ---------------------------------------------------------------------------
// Kernel 2b: WhT f16 pack for GRU
// ---------------------------------------------------------------------------
__global__ __launch_bounds__(256) void whT_kernel(const float* __restrict__ Wh,
                                                  unsigned int* __restrict__ whT) {
  int g = blockIdx.x * 256 + threadIdx.x;  // 0..98303
  int i = g / 768;
  int j = g % 768;
  float lo = Wh[(size_t)(2 * i) * 768 + j];
  float hi = Wh[(size_t)(2 * i + 1) * 768 + j];
  whT[(size_t)j * 128 + i] = pack2(lo, hi);
}

// ---------------------------------------------------------------------------
// Kernel 2c: wkT16[k][d][c] = f16(Wk_w[k][c][d])
// ---------------------------------------------------------------------------
__global__ __launch_bounds__(256) void wkT_kernel(const float* __restrict__ Wk_w,
                                                  _Float16* __restrict__ wkT) {
  int id = blockIdx.x * 256 + threadIdx.x;  // 0..393215
  int k = id >> 15;
  int rem = id & 32767;
  int c = rem >> 7;
  int d = rem & 127;
  wkT[((size_t)k * 128 + d) * 256 + c] = (_Float16)Wk_w[id];
}

// ---------------------------------------------------------------------------
// Kernel 3: GRU scan — R3 structure (3 accumulators, proven 603us; R7's
// 6-chain split SPILLED — FETCH/WRITE +3/+6MB — reverted) with two
// register-neutral edits:
//  (1) lgkm-only step barrier: raw s_barrier preceded by s_waitcnt lgkmcnt(0).
//      __syncthreads() emits vmcnt(0) too, draining the x-prefetch HBM loads
//      + c-store acks every step (~300-500cy, the unexplained tail).
//      Only the ds_write of h needs barrier ordering -> lgkmcnt(0) suffices.
//  (2) x-prefetch issued at TOP of step (~2400cy cover instead of ~500).
// ---------------------------------------------------------------------------
__global__ __launch_bounds__(1024) void gru_kernel(const _Float16* __restrict__ xp,
                                                   const unsigned int* __restrict__ whT,
                                                   const float* __restrict__ bh,
                                                   float* __restrict__ c_out,
                                                   _Float16* __restrict__ c16) {
  __shared__ __align__(16) unsigned int s_h2[2][128];  // double-buffered packed h
  int tid  = threadIdx.x;
  int b    = blockIdx.x;
  int w    = tid >> 6;    // wave 0..15
  int lane = tid & 63;
  int n15  = lane & 15;
  int q    = lane >> 4;
  int ch   = w * 16 + n15;   // channel 0..255 (each covered by 4 q-replicas)

  uint4 wf[3][8];
#pragma unroll
  for (int g = 0; g < 3; ++g) {
    const uint4* src = (const uint4*)(whT + (size_t)(g * 256 + ch) * 128);
#pragma unroll
    for (int kt = 0; kt < 8; ++kt) wf[g][kt] = src[kt * 4 + q];
  }

  if (tid < 128) s_h2[0][tid] = 0u;

  float bhr = bh[ch], bhz = bh[256 + ch], bhn = bh[512 + ch];
  const _Float16* xb = xp + (size_t)b * 512 * 768;
  float xr_n = (float)xb[ch];
  float xz_n = (float)xb[256 + ch];
  float xn_n = (float)xb[512 + ch];
  float h = 0.f;
  __syncthreads();

  for (int t = 0; t < 512; ++t) {
    const char* hb = (const char*)(&s_h2[t & 1][0]) + q * 16;

    // x prefetch for t+1 issued FIRST — consumed at next step's gates,
    // ~2 full MFMA phases of latency cover.
    float xr_c = xr_n, xz_c = xz_n, xn_c = xn_n;
    if (t < 511) {
      const _Float16* p = xb + (size_t)(t + 1) * 768;
      xr_n = (float)p[ch];
      xz_n = (float)p[256 + ch];
      xn_n = (float)p[512 + ch];
    }

    f32x4 a0 = (f32x4){0.f, 0.f, 0.f, 0.f};
    f32x4 a1 = (f32x4){0.f, 0.f, 0.f, 0.f};
    f32x4 a2 = (f32x4){0.f, 0.f, 0.f, 0.f};
#pragma unroll
    for (int kt = 0; kt < 8; ++kt) {
      f16x8 af = *(const f16x8*)(hb + kt * 64);   // uniform per q-group: broadcast
      a0 = __builtin_amdgcn_mfma_f32_16x16x32_f16(af, __builtin_bit_cast(f16x8, wf[0][kt]), a0, 0, 0, 0);
      a1 = __builtin_amdgcn_mfma_f32_16x16x32_f16(af, __builtin_bit_cast(f16x8, wf[1][kt]), a1, 0, 0, 0);
      a2 = __builtin_amdgcn_mfma_f32_16x16x32_f16(af, __builtin_bit_cast(f16x8, wf[2][kt]), a2, 0, 0, 0);
    }

    float hr = a0[0] + bhr;
    float hz = a1[0] + bhz;
    float hn = a2[0] + bhn;
    float r = __builtin_amdgcn_rcpf(1.f + __expf(-(xr_c + hr)));
    float z = __builtin_amdgcn_rcpf(1.f + __expf(-(xz_c + hz)));
    float y = xn_c + r * hn;
    y = fminf(10.f, fmaxf(-10.f, y));
    float ey = __expf(-2.f * y);
    float n = (1.f - ey) * __builtin_amdgcn_rcpf(1.f + ey);
    h = (1.f - z) * n + z * h;

    if (q == 0) {
      ((_Float16*)(&s_h2[(t & 1) ^ 1][0]))[ch] = (_Float16)h;
      c_out[((size_t)b * 512 + t) * 256 + ch] = h;
      c16[((size_t)b * 512 + t) * 256 + ch] = (_Float16)h;
    }

    // lgkm-only barrier: waits the h ds_write (LDS) but NOT the global
    // stores / x-prefetch loads (vmcnt) — those drain off-critical-path.
    asm volatile("s_waitcnt lgkmcnt(0)" ::: "memory");
    __builtin_amdgcn_s_barrier();
    __builtin_amdgcn_sched_barrier(0);   // rule-18 fence: no hoisting past barrier
  }
}

// ---------------------------------------------------------------------------
// Kernel 4: MFMA-f16 fused CPC loss — EXACT R3 v2 (proven ~196 us).
// 6000 blocks, 2/CU; no global atomics (per-block float2 partial store).
// R5 (1-block/t amortization) and R6 (T14 reg-staging) both REGRESSED.
// ---------------------------------------------------------------------------
__global__ __launch_bounds__(256, 2) void cpc_kernel(const _Float16* __restrict__ z16,
                                                     const _Float16* __restrict__ c16,
                                                     const _Float16* __restrict__ wkT,
                                                     const float* __restrict__ Wk_b,
                                                     float2* __restrict__ partials) {
  int k   = blockIdx.x;   // 0..11
  int t   = blockIdx.y;   // 0..499
  int tid = threadIdx.x;
  int wv   = tid >> 6;
  int lane = tid & 63;
  int n15  = lane & 15;
  int q    = lane >> 4;

  __shared__ __align__(16) _Float16 sA[128 * 72];
  __shared__ __align__(16) _Float16 sB[128 * 72];
  __shared__ __align__(16) _Float16 sP[128 * 136];
  __shared__ float s_bias[128];

  if (tid < 128) s_bias[tid] = Wk_b[k * 128 + tid];

  f32x4 acc[2][8];
#pragma unroll
  for (int a = 0; a < 2; ++a)
#pragma unroll
    for (int m = 0; m < 8; ++m) acc[a][m] = (f32x4){0.f, 0.f, 0.f, 0.f};

  const _Float16* wk_base = wkT + (size_t)k * 128 * 256;

  // ---- Phase B: P^T = Wk^T @ Ct^T, 4 c-panels of 64 ----
  for (int p = 0; p < 4; ++p) {
#pragma unroll
    for (int it = 0; it < 4; ++it) {
      int id = tid + it * 256;
      int r  = id >> 3;
      int c8 = (id & 7) * 8;
      *(uint4*)(&sA[r * 72 + c8]) =
          *(const uint4*)(wk_base + (size_t)r * 256 + p * 64 + c8);
      *(uint4*)(&sB[r * 72 + c8]) =
          *(const uint4*)(c16 + ((size_t)r * 512 + t) * 256 + p * 64 + c8);
    }
    __syncthreads();
#pragma unroll
    for (int ks = 0; ks < 2; ++ks) {
      f16x8 bf[2];
#pragma unroll
      for (int ntl = 0; ntl < 2; ++ntl)
        bf[ntl] = *(const f16x8*)(&sB[((wv * 2 + ntl) * 16 + n15) * 72 + ks * 32 + q * 8]);
#pragma unroll
      for (int mt = 0; mt < 8; ++mt) {
        f16x8 af = *(const f16x8*)(&sA[(mt * 16 + n15) * 72 + ks * 32 + q * 8]);
        acc[0][mt] = __builtin_amdgcn_mfma_f32_16x16x32_f16(af, bf[0], acc[0][mt], 0, 0, 0);
        acc[1][mt] = __builtin_amdgcn_mfma_f32_16x16x32_f16(af, bf[1], acc[1][mt], 0, 0, 0);
      }
    }
    __syncthreads();
  }

  // ---- bias + l2norm scale ----
  float scale[2];
#pragma unroll
  for (int ntl = 0; ntl < 2; ++ntl) {
    float ssq = 0.f;
#pragma unroll
    for (int mt = 0; mt < 8; ++mt)
#pragma unroll
      for (int r = 0; r < 4; ++r) {
        float v = acc[ntl][mt][r] + s_bias[mt * 16 + q * 4 + r];
        acc[ntl][mt][r] = v;
        ssq = fmaf(v, v, ssq);
      }
    ssq += __shfl_xor(ssq, 16);
    ssq += __shfl_xor(ssq, 32);
    scale[ntl] = 10.0f / fmaxf(sqrtf(ssq), 1e-12f);
  }

  // ---- write Pn[b][d] ----
#pragma unroll
  for (int ntl = 0; ntl < 2; ++ntl) {
    int bi = (wv * 2 + ntl) * 16 + n15;
#pragma unroll
    for (int mt = 0; mt < 8; ++mt) {
      uint2 v;
      v.x = pack2(acc[ntl][mt][0] * scale[ntl], acc[ntl][mt][1] * scale[ntl]);
      v.y = pack2(acc[ntl][mt][2] * scale[ntl], acc[ntl][mt][3] * scale[ntl]);
      *(uint2*)(&sP[bi * 136 + mt * 16 + q * 4]) = v;
    }
  }

  // ---- stage Zf ----
  int tz = t + k + 1;
#pragma unroll
  for (int it = 0; it < 4; ++it) {
    int id = tid + it * 256;
    int r  = id >> 3;
    int d8 = (id & 7) * 8;
    *(uint4*)(&sA[r * 72 + d8]) =
        *(const uint4*)(z16 + ((size_t)r * 512 + tz) * 128 + d8);
    *(uint4*)(&sB[r * 72 + d8]) =
        *(const uint4*)(z16 + ((size_t)r * 512 + tz) * 128 + 64 + d8);
  }
  __syncthreads();

  // ---- Phase D: logits ----
  f32x4 lacc[2][8];
#pragma unroll
  for (int a = 0; a < 2; ++a)
#pragma unroll
    for (int m = 0; m < 8; ++m) lacc[a][m] = (f32x4){0.f, 0.f, 0.f, 0.f};

#pragma unroll
  for (int pan = 0; pan < 2; ++pan) {
#pragma unroll
    for (int ks = 0; ks < 2; ++ks) {
      f16x8 af[2];
#pragma unroll
      for (int mtl = 0; mtl < 2; ++mtl)
        af[mtl] = *(const f16x8*)(&sP[((wv * 2 + mtl) * 16 + n15) * 136 + pan * 64 + ks * 32 + q * 8]);
#pragma unroll
      for (int nt = 0; nt < 8; ++nt) {
        f16x8 bf = pan
          ? *(const f16x8*)(&sB[(nt * 16 + n15) * 72 + ks * 32 + q * 8])
          : *(const f16x8*)(&sA[(nt * 16 + n15) * 72 + ks * 32 + q * 8]);
        lacc[0][nt] = __builtin_amdgcn_mfma_f32_16x16x32_f16(af[0], bf, lacc[0][nt], 0, 0, 0);
        lacc[1][nt] = __builtin_amdgcn_mfma_f32_16x16x32_f16(af[1], bf, lacc[1][nt], 0, 0, 0);
      }
    }
  }

  // ---- softmax stats + diag + argmax ----
  float loss_acc = 0.f, corr_acc = 0.f;
#pragma unroll
  for (int mtl = 0; mtl < 2; ++mtl) {
    int dnt = wv * 2 + mtl;
#pragma unroll
    for (int r = 0; r < 4; ++r) {
      int b = (wv * 2 + mtl) * 16 + q * 4 + r;
      float m = -1e30f; int idx = 1 << 30; float diag = 0.f;
#pragma unroll
      for (int nt = 0; nt < 8; ++nt) {
        float v = lacc[mtl][nt][r];
        int c2 = nt * 16 + n15;
        if (v > m) { m = v; idx = c2; }
        if (nt == dnt && n15 == (b & 15)) diag = v;
      }
#pragma unroll
      for (int s = 1; s <= 8; s <<= 1) {
        float om = __shfl_xor(m, s);
        int   oi = __shfl_xor(idx, s);
        if (om > m || (om == m && oi < idx)) { m = om; idx = oi; }
      }
      float e = 0.f;
#pragma unroll
      for (int nt = 0; nt < 8; ++nt) e += __expf(lacc[mtl][nt][r] - m);
#pragma unroll
      for (int s = 1; s <= 8; s <<= 1) e += __shfl_xor(e, s);
      if (n15 == (b & 15)) {
        float lse = m + __logf(e);
        loss_acc += lse - diag;
        corr_acc += (idx == b) ? 1.0f : 0.0f;
      }
    }
  }
#pragma unroll
  for (int s = 1; s <= 32; s <<= 1) {
    loss_acc += __shfl_xor(loss_acc, s);
    corr_acc += __shfl_xor(corr_acc, s);
  }

  // per-block reduction via (dead) s_bias region; ONE plain store per block
  if (lane == 0) {
    s_bias[wv * 2 + 0] = loss_acc;
    s_bias[wv * 2 + 1] = corr_acc;
  }
  __syncthreads();
  if (tid == 0) {
    float L = s_bias[0] + s_bias[2] + s_bias[4] + s_bias[6];
    float C = s_bias[1] + s_bias[3] + s_bias[5] + s_bias[7];
    partials[k * TP_ + t] = make_float2(L, C);
  }
}

// ---------------------------------------------------------------------------
// Kernel 5: final reduction of 6000 per-block partials -> out[0..1]
// ---------------------------------------------------------------------------
__global__ __launch_bounds__(256) void reduce_kernel(const float2* __restrict__ partials,
                                                     float* __restrict__ out) {
  float l = 0.f, c = 0.f;
  for (int i = threadIdx.x; i < K_ * TP_; i += 256) {
    float2 v = partials[i];
    l += v.x; c += v.y;
  }
#pragma unroll
  for (int s = 1; s <= 32; s <<= 1) {
    l += __shfl_xor(l, s);
    c += __shfl_xor(c, s);
  }
  __shared__ float sl[4], sc[4];
  int wv = threadIdx.x >> 6;
  if ((threadIdx.x & 63) == 0) { sl[wv] = l; sc[wv] = c; }
  __syncthreads();
  if (threadIdx.x == 0) {
    float L = sl[0] + sl[1] + sl[2] + sl[3];
    float C = sc[0] + sc[1] + sc[2] + sc[3];
    out[0] = L * (float)(1.0 / (double)N_SAMPLES);
    out[1] = C * (float)(100.0 / (double)N_SAMPLES);
  }
}

// ---------------------------------------------------------------------------
extern "C" void kernel_launch(void* const* d_in, const int* in_sizes, int n_in,
                              void* d_out, int out_size, void* d_ws, size_t ws_size,
                              hipStream_t stream) {
  (void)in_sizes; (void)n_in; (void)out_size; (void)ws_size;
  const float* rr  = (const float*)d_in[0];
  const float* We  = (const float*)d_in[1];
  const float* be  = (const float*)d_in[2];
  const float* Wi  = (const float*)d_in[3];
  const float* Wh  = (const float*)d_in[4];
  const float* bi  = (const float*)d_in[5];
  const float* bh  = (const float*)d_in[6];
  const float* Wkw = (const float*)d_in[7];
  const float* Wkb = (const float*)d_in[8];

  float* out = (float*)d_out;
  float* z   = out + 2;                              // (B,T,D) fp32
  float* c   = z + (size_t)B_ * T_ * D_;             // (B,T,C) fp32

  // workspace layout (bytes):
  //   whT    @ 0          (384 KB)
  //   wkT16  @ 393216     (768 KB)
  //   z16    @ 1179648    (16 MB)
  //   c16    @ 17956864   (32 MB)
  //   xp     @ 51511296   (100.7 MB)  <- dead after gru; first 48KB reused
  //                                      as cpc partials (float2[6000])
  //   wiT16  @ 152174592  (192 KB)
  char* ws = (char*)d_ws;
  unsigned int* whT   = (unsigned int*)ws;
  _Float16*     wkT16 = (_Float16*)(ws + 393216);
  _Float16*     z16   = (_Float16*)(ws + 1179648);
  _Float16*     c16   = (_Float16*)(ws + 17956864);
  _Float16*     xp    = (_Float16*)(ws + 51511296);
  _Float16*     wiT16 = (_Float16*)(ws + 152174592);
  float2*       parts = (float2*)(ws + 51511296);    // overlays dead xp

  hipMemsetAsync(d_out, 0, 2 * sizeof(float), stream);
  z_kernel<<<B_ * T_, 128, 0, stream>>>(rr, We, be, z, z16);
  wiT_kernel<<<384, 256, 0, stream>>>(Wi, wiT16);
  whT_kernel<<<384, 256, 0, stream>>>(Wh, whT);
  wkT_kernel<<<1536, 256, 0, stream>>>(Wkw, wkT16);
  xproj_mfma<<<dim3(512, 6), 256, 0, stream>>>(z16, wiT16, bi, xp);
  gru_kernel<<<B_, 1024, 0, stream>>>(xp, whT, bh, c, c16);
  cpc_kernel<<<dim3(K_, TP_), 256, 0, stream>>>(z16, c16, wkT16, Wkb, parts);
  reduce_kernel<<<1, 256, 0, stream>>>(parts, out);
}